// Round 2
// baseline (188.955 us; speedup 1.0000x reference)
//
#include <hip/hip_runtime.h>

#define KK 8
#define NA 8
#define NB 64
#define NH 256
#define NW 256
#define HP (NH - KK + 1)   // 249
#define WP (NW - KK + 1)   // 249

typedef __attribute__((ext_vector_type(4))) float f32x4;
typedef __attribute__((ext_vector_type(2))) float f32x2;

// Stage 1: sm[a][y][x] = exp( (1/64) * sum_b x[a][b][y][x] )
// One float4 per thread, full 64-channel reduction. 512 blocks = 2 waves/SIMD.
// x is read exactly once globally -> non-temporal loads (nt) so the 134 MB
// stream doesn't thrash L1/L2 (keeps sm/cnt lines resident for stage 2).
// unroll 32 keeps 32 dwordx4 loads in flight per lane.
__global__ __launch_bounds__(256) void k_mean_exp(const float* __restrict__ x,
                                                  float* __restrict__ sm) {
    int tid = blockIdx.x * 256 + threadIdx.x;   // 0 .. A*H*W/4-1
    int a = tid >> 14;                          // H*W/4 = 16384 float4 per image
    int p4 = tid & 16383;
    const f32x4* xp = (const f32x4*)(x + (size_t)a * NB * (NH * NW)) + p4;
    f32x4 acc = {0.f, 0.f, 0.f, 0.f};
    #pragma unroll 32
    for (int b = 0; b < NB; ++b) {
        f32x4 v = __builtin_nontemporal_load(xp + (size_t)b * (NH * NW / 4));
        acc += v;
    }
    const float s = 1.0f / NB;
    f32x4 r;
    r.x = __expf(acc.x * s);
    r.y = __expf(acc.y * s);
    r.z = __expf(acc.z * s);
    r.w = __expf(acc.w * s);
    ((f32x4*)sm)[tid] = r;
}

// Stage 2 (fused): per 32x32 output tile, stage the 46x46 sm tile (7-halo)
// into LDS, then separable box sums. All four box-sum passes use 2-wide
// sliding windows (two adjacent 8-sums share 7 terms: 10 LDS reads for 2
// outputs instead of 16) and fit one 1024-thread sweep each:
//   B: hrs 46x39 horiz sums      -> 920 pair-items
//   C: t = cnt/sc (vert of hrs)  -> 780 pair-items (cnt prefetched at entry)
//   D: vs 32x39 (vert of t)      -> 624 pair-items
//   E: out = sm_c * horiz of vs  -> 512 pair-items, float2 nt store
// LDS wave-inst/block ~509 (was ~751). 512 blocks x 16 waves = full occupancy.
__global__ __launch_bounds__(1024) void k_fused(const float* __restrict__ sm,
                                                const float* __restrict__ cnt,
                                                float* __restrict__ out) {
    __shared__ float s_sm[46 * 48];
    __shared__ float hrs[46 * 40];
    __shared__ float t_s[39 * 40];
    __shared__ float vs[32 * 40];
    const int tid = threadIdx.y * 32 + threadIdx.x;
    const int a = blockIdx.z;
    const int y0 = blockIdx.y * 32, x0 = blockIdx.x * 32;
    const float* sa = sm + (size_t)a * (NH * NW);
    const float* ca = cnt + (size_t)a * (HP * WP);

    // Prefetch the two cnt values pass C will need; the HBM latency hides
    // under the staging loop + pass B instead of stalling pass C.
    float cv0 = 0.f, cv1 = 0.f;
    {
        int q = tid / 39, c = tid - q * 39;   // q<20 when tid<780
        int r0 = q * 2;
        int ph = y0 - 7 + r0, pw = x0 - 7 + c;
        if (tid < 780 && (unsigned)pw < (unsigned)WP) {
            if ((unsigned)ph < (unsigned)HP) cv0 = ca[ph * WP + pw];
            if (r0 + 1 < 39 && (unsigned)(ph + 1) < (unsigned)HP)
                cv1 = ca[(ph + 1) * WP + pw];
        }
    }

    // sm tile: 46x46, coords clamped (clamped entries only feed invalid t)
    for (int idx = tid; idx < 46 * 46; idx += 1024) {
        int r = idx / 46, cc = idx - r * 46;
        int rg = y0 - 7 + r;  rg = rg < 0 ? 0 : (rg > NH - 1 ? NH - 1 : rg);
        int cg = x0 - 7 + cc; cg = cg < 0 ? 0 : (cg > NW - 1 ? NW - 1 : cg);
        s_sm[r * 48 + cc] = sa[rg * NW + cg];
    }
    __syncthreads();

    // B: hrs[r][c] = sum_j sm[r][c+j], 46 rows x 39 cols as 46x20 pairs
    if (tid < 920) {
        int r = tid / 20, p = tid - r * 20;
        int c0 = p * 2;
        const float* row = &s_sm[r * 48 + c0];
        float s0 = row[0] + row[1] + row[2] + row[3] +
                   row[4] + row[5] + row[6] + row[7];
        hrs[r * 40 + c0] = s0;
        if (c0 + 1 < 39) hrs[r * 40 + c0 + 1] = s0 - row[0] + row[8];
    }
    __syncthreads();

    // C: t = cnt / (vert 8-sum of hrs), 39x39 as 20x39 row-pairs
    if (tid < 780) {
        int q = tid / 39, c = tid - q * 39;
        int r0 = q * 2;
        const float* col = &hrs[r0 * 40 + c];
        float s0 = col[0 * 40] + col[1 * 40] + col[2 * 40] + col[3 * 40] +
                   col[4 * 40] + col[5 * 40] + col[6 * 40] + col[7 * 40];
        t_s[r0 * 40 + c] = cv0 / s0;
        if (r0 + 1 < 39) {
            float s1 = s0 - col[0 * 40] + col[8 * 40];
            t_s[(r0 + 1) * 40 + c] = cv1 / s1;
        }
    }
    __syncthreads();

    // D: vs[r][c] = vert 8-sum of t, 32x39 as 16x39 row-pairs
    if (tid < 624) {
        int q = tid / 39, c = tid - q * 39;
        int r0 = q * 2;                       // 0..30, r0+8 <= 38 valid
        const float* col = &t_s[r0 * 40 + c];
        float s0 = col[0 * 40] + col[1 * 40] + col[2 * 40] + col[3 * 40] +
                   col[4 * 40] + col[5 * 40] + col[6 * 40] + col[7 * 40];
        vs[r0 * 40 + c] = s0;
        vs[(r0 + 1) * 40 + c] = s0 - col[0 * 40] + col[8 * 40];
    }
    __syncthreads();

    // E: out = sm_center * horiz 8-sum of vs, 32x32 as 32x16 col-pairs
    if (tid < 512) {
        int r = tid >> 4, p = tid & 15;
        int c0 = p * 2;                       // 0..30, c0+8 <= 38 valid
        const float* row = &vs[r * 40 + c0];
        float s0 = row[0] + row[1] + row[2] + row[3] +
                   row[4] + row[5] + row[6] + row[7];
        float s1 = s0 - row[0] + row[8];
        f32x2 ov;
        ov.x = s_sm[(r + 7) * 48 + c0 + 7] * s0;
        ov.y = s_sm[(r + 7) * 48 + c0 + 8] * s1;
        __builtin_nontemporal_store(ov,
            (f32x2*)&out[((size_t)a * NH + (y0 + r)) * NW + (x0 + c0)]);
    }
}

extern "C" void kernel_launch(void* const* d_in, const int* in_sizes, int n_in,
                              void* d_out, int out_size, void* d_ws, size_t ws_size,
                              hipStream_t stream) {
    const float* x = (const float*)d_in[0];   // (8,64,256,256) f32
    const float* c = (const float*)d_in[1];   // (8,1,249,249)  f32
    float* out = (float*)d_out;               // (8,1,256,256)  f32
    float* sm  = (float*)d_ws;                // 2 MB

    k_mean_exp<<<(NA * NH * NW / 4) / 256, 256, 0, stream>>>(x, sm);
    dim3 grid(NW / 32, NH / 32, NA);          // (8,8,8)
    dim3 block(32, 32);
    k_fused<<<grid, block, 0, stream>>>(sm, c, out);
}